// Round 13
// baseline (5245.614 us; speedup 1.0000x reference)
//
#include <hip/hip_runtime.h>
#include <hip/hip_bf16.h>
#include <cstdint>
#include <cstddef>

// Problem constants
#define T_LEN 1024
#define B_SZ  64
#define H_DIM 512
#define D_IN  512
#define YSLOTS 16

// Decomposition (round-11 proven): 256 blocks x 256 threads, ONE block per CU.
//   layer = bid>>7 ; lbid = bid&127 ; grp = lbid&7 (dir*4+bg) ; cg = lbid>>3 (0..15)
// Block owns 16 batch rows (bg) x 32 h-cols of ONE layer/dir. Sync community =
// 16 blocks. L0/L1 run concurrently on disjoint CUs, coupled by a 16-slot y ring.
#define GROUP 16

typedef __attribute__((ext_vector_type(8))) short short8;
typedef __attribute__((ext_vector_type(4))) float f32x4;
typedef unsigned long long ull;

// LDS: Whh 6 subtiles (gate,colhalf) x 16K = 96K | X 16K | H 16K | D 12K
#define OFF_WHH 0
#define OFF_X   98304
#define OFF_H   114688
#define OFF_D   131072
#define SMEM_BYTES 143360

__device__ __forceinline__ int swz(int row, int b) {
  return b ^ ((row & 7) << 4);   // 16B-granule XOR, breaks stride-1024 conflicts
}

__device__ __forceinline__ unsigned short f2bf(float f) {
  unsigned u = __float_as_uint(f);
  return (unsigned short)((u + 0x7FFFu + ((u >> 16) & 1u)) >> 16);   // RNE
}

__device__ __forceinline__ short8 pack8(float4 a, float4 b) {
  short8 v;
  v[0] = (short)f2bf(a.x); v[1] = (short)f2bf(a.y);
  v[2] = (short)f2bf(a.z); v[3] = (short)f2bf(a.w);
  v[4] = (short)f2bf(b.x); v[5] = (short)f2bf(b.y);
  v[6] = (short)f2bf(b.z); v[7] = (short)f2bf(b.w);
  return v;
}

__device__ __forceinline__ unsigned cvtpk(float lo, float hi) {
  unsigned r;
  asm("v_cvt_pk_bf16_f32 %0, %1, %2" : "=v"(r) : "v"(lo), "v"(hi));   // RNE
  return r;
}
__device__ __forceinline__ short8 cvtpk8(float4 a, float4 b) {
  union { unsigned u[4]; short8 s; } cv;
  cv.u[0] = cvtpk(a.x, a.y); cv.u[1] = cvtpk(a.z, a.w);
  cv.u[2] = cvtpk(b.x, b.y); cv.u[3] = cvtpk(b.z, b.w);
  return cv.s;
}

__device__ __forceinline__ float sigm(float x) { return 1.0f / (1.0f + __expf(-x)); }
__device__ __forceinline__ float fast_tanh(float x) { return 1.0f - 2.0f / (__expf(2.0f * x) + 1.0f); }

__global__ __launch_bounds__(256, 1)
void gru_pipe(const float* __restrict__ x,
              const float* __restrict__ enc,
              const float* __restrict__ WihF, const float* __restrict__ WhhF,
              const float* __restrict__ bihF, const float* __restrict__ bhhF,
              const float* __restrict__ WihB, const float* __restrict__ WhhB,
              const float* __restrict__ bihB, const float* __restrict__ bhhB,
              float* __restrict__ dout,
              unsigned* __restrict__ flags,
              unsigned short* __restrict__ hbuf,
              unsigned short* __restrict__ yring)
{
  __shared__ alignas(16) char smem[SMEM_BYTES];

  const int bid   = blockIdx.x;
  const int layer = bid >> 7;
  const int lbid  = bid & 127;
  const int grp   = lbid & 7;        // dir*4+bg (mod-8: XCD affinity, perf only)
  const int dir   = grp >> 2;
  const int bg    = grp & 3;
  const int cg    = lbid >> 3;       // 0..15 (32-col groups)
  const int tid   = threadIdx.x;
  const int wv    = tid >> 6;        // wave 0..3
  const int tb    = tid >> 4;        // staging/batch row 0..15
  const int tc    = tid & 15;        // col-unit 0..15
  const int lane  = tid & 63;
  const int frow  = lane & 15;       // MFMA fragment row
  const int q     = lane >> 4;       // MFMA k-quarter
  const int hc0   = cg * 32;
  const int c0    = hc0 + tc;        // this thread's two gate-cols
  const int c1    = c0 + 16;
  const int brow  = bg * 16 + tb;
  const int dircol = dir * H_DIM;
  // wave job: main gate gw (0=r,1=z) on colhalf cw; n-gate quarter (colhalf cw, k-half kh)
  const int gw = wv & 1, cw = wv >> 1, kh = wv & 1;

  const float* Wih = (dir ? WihB : WihF) + (size_t)layer * 3 * H_DIM * D_IN;
  const float* Whh = (dir ? WhhB : WhhF) + (size_t)layer * 3 * H_DIM * H_DIM;
  const float* bih = (dir ? bihB : bihF) + (size_t)layer * 3 * H_DIM;
  const float* bhh = (dir ? bhhB : bhhF) + (size_t)layer * 3 * H_DIM;

  unsigned* fl  = flags + (layer * 8 + grp) * 64;  // own group's 16 producer flags
  unsigned* fl0 = flags + grp * 64;                // L0 counterpart
  unsigned* fl1 = flags + (8 + grp) * 64;          // L1 counterpart

  // ---- Stage Whh: 6 subtiles (gate g, colhalf ch), 16 rows x 1024B each ----
  #pragma unroll
  for (int g = 0; g < 3; ++g) {
    #pragma unroll
    for (int ch = 0; ch < 2; ++ch) {
      const float* s = Whh + (size_t)(g * H_DIM + hc0 + ch * 16 + tb) * H_DIM + tc * 32;
      char* r = smem + OFF_WHH + (g * 2 + ch) * 16384 + tb * 1024;
      #pragma unroll
      for (int u = 0; u < 4; ++u) {
        float4 a = ((const float4*)s)[u * 2];
        float4 b = ((const float4*)s)[u * 2 + 1];
        *(short8*)(r + swz(tb, tc * 64 + u * 16)) = pack8(a, b);
      }
    }
  }

  // ---- Wih B-fragments in registers: main job 16 chunks + n-quarter 8 chunks ----
  short8 wfM[16], wfN[8];
  {
    const float* pm = Wih + (size_t)(gw * H_DIM + hc0 + cw * 16 + frow) * D_IN;
    #pragma unroll
    for (int kc = 0; kc < 16; ++kc)
      wfM[kc] = cvtpk8(*(const float4*)(pm + kc * 32 + q * 8),
                       *(const float4*)(pm + kc * 32 + q * 8 + 4));
    const float* pn = Wih + (size_t)(2 * H_DIM + hc0 + cw * 16 + frow) * D_IN;
    #pragma unroll
    for (int j = 0; j < 8; ++j) {
      const int kc = kh * 8 + j;
      wfN[j] = cvtpk8(*(const float4*)(pn + kc * 32 + q * 8),
                      *(const float4*)(pn + kc * 32 + q * 8 + 4));
    }
  }

  // ---- biases (two cols per thread) and initial hidden state ----
  const float b_r0  = bih[c0] + bhh[c0];
  const float b_z0  = bih[H_DIM + c0] + bhh[H_DIM + c0];
  const float b_xn0 = bih[2 * H_DIM + c0];
  const float b_hn0 = bhh[2 * H_DIM + c0];
  const float b_r1  = bih[c1] + bhh[c1];
  const float b_z1  = bih[H_DIM + c1] + bhh[H_DIM + c1];
  const float b_xn1 = bih[2 * H_DIM + c1];
  const float b_hn1 = bhh[2 * H_DIM + c1];
  float h0 = enc[(size_t)layer * B_SZ * 2 * H_DIM + (size_t)brow * 2 * H_DIM + dircol + c0];
  float h1 = enc[(size_t)layer * B_SZ * 2 * H_DIM + (size_t)brow * 2 * H_DIM + dircol + c1];

  // ---- exchange bases (bf16, 512 cols x 16 rows per state) ----
  auto hbase = [&](int par) -> unsigned short* {
    return hbuf + (size_t)((((layer * 2 + par) * 2 + dir) * 4 + bg) * 16) * 512;
  };
  auto ybase = [&](int slot) -> unsigned short* {
    return yring + (size_t)(((slot * 2 + dir) * 4 + bg) * 16) * 512;
  };

  // ---- publish both colhalves (r3-proven shfl 4-pack, 8B agent stores) ----
  auto pub = [&](float v0, float v1, unsigned short* hrow, unsigned short* yrow) {
    unsigned a = f2bf(v0), b = f2bf(v1);
    unsigned a1 = __shfl_down(a, 1), a2 = __shfl_down(a, 2), a3 = __shfl_down(a, 3);
    unsigned b1 = __shfl_down(b, 1), b2 = __shfl_down(b, 2), b3 = __shfl_down(b, 3);
    if ((tc & 3) == 0) {
      ull pa = (ull)a | ((ull)a1 << 16) | ((ull)a2 << 32) | ((ull)a3 << 48);
      ull pb = (ull)b | ((ull)b1 << 16) | ((ull)b2 << 32) | ((ull)b3 << 48);
      __hip_atomic_store((ull*)(hrow + hc0 + tc),      pa, __ATOMIC_RELAXED, __HIP_MEMORY_SCOPE_AGENT);
      __hip_atomic_store((ull*)(hrow + hc0 + 16 + tc), pb, __ATOMIC_RELAXED, __HIP_MEMORY_SCOPE_AGENT);
      if (yrow) {
        __hip_atomic_store((ull*)(yrow + hc0 + tc),      pa, __ATOMIC_RELAXED, __HIP_MEMORY_SCOPE_AGENT);
        __hip_atomic_store((ull*)(yrow + hc0 + 16 + tc), pb, __ATOMIC_RELAXED, __HIP_MEMORY_SCOPE_AGENT);
      }
    }
  };

  // gather a full 16x512 bf16 state into an LDS tile (r3-proven 8B agent loads)
  auto gatherRow = [&](const unsigned short* src, int ldsOff) {
    const ull* hb = (const ull*)(src + (size_t)tb * 512 + tc * 32);
    ull hv[8];
    #pragma unroll
    for (int u = 0; u < 8; ++u)
      hv[u] = __hip_atomic_load(hb + u, __ATOMIC_RELAXED, __HIP_MEMORY_SCOPE_AGENT);
    char* lh = smem + ldsOff + tb * 1024;
    #pragma unroll
    for (int u = 0; u < 4; ++u) {
      ull tmp[2] = {hv[2 * u], hv[2 * u + 1]};
      *(short8*)(lh + swz(tb, tc * 64 + u * 16)) = *(const short8*)tmp;
    }
  };
  // fused h + y gather: issue BOTH load sets back-to-back (RTs overlap), then repack
  auto gatherRow2 = [&](const unsigned short* srcH, const unsigned short* srcY) {
    const ull* hb = (const ull*)(srcH + (size_t)tb * 512 + tc * 32);
    const ull* yb = (const ull*)(srcY + (size_t)tb * 512 + tc * 32);
    ull hv[8], yv[8];
    #pragma unroll
    for (int u = 0; u < 8; ++u)
      hv[u] = __hip_atomic_load(hb + u, __ATOMIC_RELAXED, __HIP_MEMORY_SCOPE_AGENT);
    #pragma unroll
    for (int u = 0; u < 8; ++u)
      yv[u] = __hip_atomic_load(yb + u, __ATOMIC_RELAXED, __HIP_MEMORY_SCOPE_AGENT);
    char* lh = smem + OFF_H + tb * 1024;
    char* lx = smem + OFF_X + tb * 1024;
    #pragma unroll
    for (int u = 0; u < 4; ++u) {
      ull t0[2] = {hv[2 * u], hv[2 * u + 1]};
      *(short8*)(lh + swz(tb, tc * 64 + u * 16)) = *(const short8*)t0;
      ull t1[2] = {yv[2 * u], yv[2 * u + 1]};
      *(short8*)(lx + swz(tb, tc * 64 + u * 16)) = *(const short8*)t1;
    }
  };

  // x-part: fused main gate (16 chunks) + xn quarter (8 chunks), B from registers
  auto xpart = [&](f32x4& aM, f32x4& aXN) {
    char* xr = smem + OFF_X + frow * 1024;
    #pragma unroll
    for (int kc = 0; kc < 16; ++kc) {
      short8 a = *(const short8*)(xr + swz(frow, kc * 64 + q * 16));
      aM = __builtin_amdgcn_mfma_f32_16x16x32_bf16(a, wfM[kc], aM, 0, 0, 0);
    }
    #pragma unroll
    for (int j = 0; j < 8; ++j) {
      const int kc = kh * 8 + j;
      short8 a = *(const short8*)(xr + swz(frow, kc * 64 + q * 16));
      aXN = __builtin_amdgcn_mfma_f32_16x16x32_bf16(a, wfN[j], aXN, 0, 0, 0);
    }
  };
  // h-part: fused main gate + hn quarter, B from Whh LDS subtiles
  auto hpart = [&](f32x4& aM, f32x4& aHN) {
    char* hr = smem + OFF_H + frow * 1024;
    char* wm = smem + OFF_WHH + (gw * 2 + cw) * 16384 + frow * 1024;
    char* wn = smem + OFF_WHH + (4 + cw) * 16384 + frow * 1024;
    #pragma unroll
    for (int kc = 0; kc < 16; ++kc) {
      const int o = swz(frow, kc * 64 + q * 16);
      short8 a = *(const short8*)(hr + o);
      short8 b = *(const short8*)(wm + o);
      aM = __builtin_amdgcn_mfma_f32_16x16x32_bf16(a, b, aM, 0, 0, 0);
    }
    #pragma unroll
    for (int j = 0; j < 8; ++j) {
      const int kc = kh * 8 + j;
      const int o = swz(frow, kc * 64 + q * 16);
      short8 a = *(const short8*)(hr + o);
      short8 b = *(const short8*)(wn + o);
      aHN = __builtin_amdgcn_mfma_f32_16x16x32_bf16(a, b, aHN, 0, 0, 0);
    }
  };
  auto dwrite = [&](const f32x4& aM, const f32x4& aXN, const f32x4& aHN) {
    float* d0 = (float*)(smem + OFF_D + wv * 1024);
    float* d1 = (float*)(smem + OFF_D + 4096 + wv * 1024);
    float* d2 = (float*)(smem + OFF_D + 8192 + wv * 1024);
    #pragma unroll
    for (int r = 0; r < 4; ++r) {
      const int idx = (q * 4 + r) * 16 + ((frow + 4 * q) & 15);
      d0[idx] = aM[r]; d1[idx] = aXN[r]; d2[idx] = aHN[r];
    }
  };

  // ---- prologue: publish h(0) parity 0; flag=1; x-part for step 0 ----
  pub(h0, h1, hbase(0) + (size_t)tb * 512, nullptr);
  asm volatile("s_waitcnt vmcnt(0)" ::: "memory");
  __syncthreads();   // also covers Whh LDS staging
  if (tid == 0)
    __hip_atomic_store(&fl[cg], 1u, __ATOMIC_RELAXED, __HIP_MEMORY_SCOPE_AGENT);

  f32x4 aM = {0.f,0.f,0.f,0.f}, aXN = {0.f,0.f,0.f,0.f};
  if (layer == 0) {
    const float* xrow = x + ((size_t)brow * T_LEN + (dir ? (T_LEN - 1) : 0)) * D_IN;
    const float4* s4 = (const float4*)(xrow + tc * 32);
    char* lx = smem + OFF_X + tb * 1024;
    #pragma unroll
    for (int u = 0; u < 4; ++u) {
      float4 a = s4[u * 2];
      float4 b = s4[u * 2 + 1];
      *(short8*)(lx + swz(tb, tc * 64 + u * 16)) = pack8(a, b);
    }
    __syncthreads();
    xpart(aM, aXN);
  } else {
    if (tid < GROUP) {
      while (__hip_atomic_load(&fl0[tid], __ATOMIC_RELAXED, __HIP_MEMORY_SCOPE_AGENT) < 2u)
        __builtin_amdgcn_s_sleep(1);
    }
    __syncthreads();
    gatherRow(ybase(0), OFF_X);
    __syncthreads();
    xpart(aM, aXN);
  }

  for (int t = 0; t < T_LEN; ++t) {
    // ---- L0: issue x(t+1) prefetch into registers (RT overlaps spin+gather) ----
    float4 xf[8];
    if (layer == 0 && t + 1 < T_LEN) {
      const float* xrow = x + ((size_t)brow * T_LEN + (dir ? (T_LEN - 2 - t) : (t + 1))) * D_IN;
      const float4* s4 = (const float4*)(xrow + tc * 32);
      #pragma unroll
      for (int u = 0; u < 8; ++u) xf[u] = s4[u];
    }

    // ---- merged spin: own h flags; L1 adds y-availability; L0 adds backpressure ----
    {
      const bool needY  = (layer == 1) && (t + 1 < T_LEN);
      const bool needBP = (layer == 0) && (t >= 16) && ((t & 7) == 0);
      if (tid < GROUP) {
        const unsigned tgtH  = (unsigned)(t + 1);
        const unsigned tgtY  = (unsigned)(t + 3);
        const unsigned tgtBP = (unsigned)(t - 7);
        for (;;) {
          bool ok = __hip_atomic_load(&fl[tid], __ATOMIC_RELAXED, __HIP_MEMORY_SCOPE_AGENT) >= tgtH;
          if (needY)
            ok &= __hip_atomic_load(&fl0[tid], __ATOMIC_RELAXED, __HIP_MEMORY_SCOPE_AGENT) >= tgtY;
          if (needBP)
            ok &= __hip_atomic_load(&fl1[tid], __ATOMIC_RELAXED, __HIP_MEMORY_SCOPE_AGENT) >= tgtBP;
          if (ok) break;
          __builtin_amdgcn_s_sleep(1);
        }
      }
    }
    __syncthreads();   // B1

    // ---- gather h(t) (+ L1: y(t+1)) — load RTs overlapped, one window ----
    if (layer == 1 && t + 1 < T_LEN)
      gatherRow2(hbase(t & 1), ybase((t + 1) & (YSLOTS - 1)));
    else
      gatherRow(hbase(t & 1), OFF_H);
    __syncthreads();   // B2: H (and X for L1) ready

    // ---- h-part MFMAs + D write; L0 packs xf -> X tile ----
    f32x4 aHN = {0.f,0.f,0.f,0.f};
    hpart(aM, aHN);
    dwrite(aM, aXN, aHN);
    if (layer == 0 && t + 1 < T_LEN) {
      char* lx = smem + OFF_X + tb * 1024;
      #pragma unroll
      for (int u = 0; u < 4; ++u)
        *(short8*)(lx + swz(tb, tc * 64 + u * 16)) = pack8(xf[u * 2], xf[u * 2 + 1]);
    }
    __syncthreads();   // B3: D ready + X ready

    // ---- gates (two cols per thread) ----
    {
      const float* Df = (const float*)(smem + OFF_D);
      const int e = tb * 16 + ((tc + 4 * (tb >> 2)) & 15);
      const float r0 = sigm(Df[e] + b_r0);
      const float z0 = sigm(Df[256 + e] + b_z0);
      const float n0 = fast_tanh(Df[1024 + e] + Df[1280 + e] + b_xn0 +
                                 r0 * (Df[2048 + e] + Df[2304 + e] + b_hn0));
      h0 = (1.0f - z0) * n0 + z0 * h0;
      const float r1 = sigm(Df[512 + e] + b_r1);
      const float z1 = sigm(Df[768 + e] + b_z1);
      const float n1 = fast_tanh(Df[1536 + e] + Df[1792 + e] + b_xn1 +
                                 r1 * (Df[2560 + e] + Df[2816 + e] + b_hn1));
      h1 = (1.0f - z1) * n1 + z1 * h1;
    }

    // ---- publish h(t+1) (+ y0(t) ring for L0); L1 writes y1 out ----
    const int torig = dir ? (T_LEN - 1 - t) : t;
    pub(h0, h1, hbase((t + 1) & 1) + (size_t)tb * 512,
        (layer == 0) ? (ybase(t & (YSLOTS - 1)) + (size_t)tb * 512) : nullptr);
    if (layer == 1) {
      dout[(size_t)brow * T_LEN * 2 * H_DIM + (size_t)torig * 2 * H_DIM + dircol + c0] = h0;
      dout[(size_t)brow * T_LEN * 2 * H_DIM + (size_t)torig * 2 * H_DIM + dircol + c1] = h1;
    }
    if (t == T_LEN - 1) {
      dout[(size_t)B_SZ * T_LEN * 2 * H_DIM +
           (size_t)(layer * B_SZ + brow) * 2 * H_DIM + dircol + c0] = h0;
      dout[(size_t)B_SZ * T_LEN * 2 * H_DIM +
           (size_t)(layer * B_SZ + brow) * 2 * H_DIM + dircol + c1] = h1;
    }
    asm volatile("s_waitcnt vmcnt(0)" ::: "memory");
    __syncthreads();   // B4
    if (tid == 0)
      __hip_atomic_store(&fl[cg], (unsigned)(t + 2), __ATOMIC_RELAXED, __HIP_MEMORY_SCOPE_AGENT);

    // ---- tail: x-part for step t+1 (X tile already prepared) ----
    if (t + 1 < T_LEN) {
      aM[0]=0.f;  aM[1]=0.f;  aM[2]=0.f;  aM[3]=0.f;
      aXN[0]=0.f; aXN[1]=0.f; aXN[2]=0.f; aXN[3]=0.f;
      xpart(aM, aXN);
    }
  }
}

extern "C" void kernel_launch(void* const* d_in, const int* in_sizes, int n_in,
                              void* d_out, int out_size, void* d_ws, size_t ws_size,
                              hipStream_t stream) {
  (void)in_sizes; (void)n_in; (void)out_size; (void)ws_size;
  const float* x    = (const float*)d_in[0];
  const float* enc  = (const float*)d_in[1];
  const float* WihF = (const float*)d_in[2];
  const float* WhhF = (const float*)d_in[3];
  const float* bihF = (const float*)d_in[4];
  const float* bhhF = (const float*)d_in[5];
  const float* WihB = (const float*)d_in[6];
  const float* WhhB = (const float*)d_in[7];
  const float* bihB = (const float*)d_in[8];
  const float* bhhB = (const float*)d_in[9];
  float* out = (float*)d_out;

  unsigned* flags = (unsigned*)d_ws;                                   // 4KB
  unsigned short* hbuf  = (unsigned short*)((char*)d_ws + 4096);       // 512KB
  unsigned short* yring = (unsigned short*)((char*)d_ws + 4096 + 524288); // 2MB
  hipMemsetAsync(d_ws, 0, 4096, stream);   // zero flags each replay (data is flag-gated)

  dim3 grid(256), block(256);
  gru_pipe<<<grid, block, 0, stream>>>(x, enc, WihF, WhhF, bihF, bhhF,
                                       WihB, WhhB, bihB, bhhB, out, flags, hbuf, yring);
}